// Round 6
// baseline (139.953 us; speedup 1.0000x reference)
//
#include <hip/hip_runtime.h>
#include <stdint.h>

#define WW 256
#define CIN 128
#define COUT 256
#define OHW 64516          // 254*254
#define KTOT 1152          // 128*9
#define BM 128
#define BN 128
#define BK 64
#define NSTEP 18           // KTOT/BK
#define NWG 1010           // 505 m-blocks * 2 n-blocks
#define BUFSZ 32768        // per tile: A 16KB + B 16KB

typedef __attribute__((ext_vector_type(8))) short short8;
typedef __attribute__((ext_vector_type(4))) float float4v;
typedef __attribute__((ext_vector_type(4))) float f32x4;
typedef __attribute__((ext_vector_type(2))) unsigned int uint2v;

__device__ __forceinline__ short f2bf(float f) {
    unsigned u = __builtin_bit_cast(unsigned, f);
    unsigned r = u + 0x7fffu + ((u >> 16) & 1u);   // RNE
    return (short)(r >> 16);
}

// Wt[co][k'] bf16, k' = q*128 + c. Output-indexed => coalesced 2B writes;
// scattered 4B reads land in the L2-resident 1.2MB source.
__global__ void prep_weights(const int* __restrict__ kq, unsigned short* __restrict__ wt) {
    int o  = blockIdx.x * 256 + threadIdx.x;   // o = co*1152 + kp
    int co = o / KTOT;
    int kp = o - co * KTOT;
    int q  = kp >> 7;
    int c  = kp & 127;
    wt[o] = (unsigned short)f2bf((float)kq[(c * 9 + q) * 256 + co]);
}

__device__ __forceinline__ void gload16(const void* g, void* l) {
    __builtin_amdgcn_global_load_lds(
        (const __attribute__((address_space(1))) unsigned int*)g,
        (__attribute__((address_space(3))) unsigned int*)l, 16, 0, 0);
}

__device__ __forceinline__ unsigned cvtpk(float lo, float hi) {
    unsigned r;
    asm("v_cvt_pk_bf16_f32 %0, %1, %2" : "=v"(r) : "v"(lo), "v"(hi));
    return r;
}

#define SB  __builtin_amdgcn_sched_barrier(0)
#define BAR __builtin_amdgcn_s_barrier()
#define WAIT_VM(n) asm volatile("s_waitcnt vmcnt(" #n ")" ::: "memory")
#define WAIT_LGKM  asm volatile("s_waitcnt lgkmcnt(0)" ::: "memory")

__global__ __launch_bounds__(256, 2) void conv_gemm(
    const float* __restrict__ x,
    const unsigned short* __restrict__ wt,
    const float* __restrict__ scale_p,
    const float* __restrict__ bias,
    float* __restrict__ out)
{
    // Per buffer: A [128 rows][128 B] at +0, B [128 co][128 B] at +16384.
    // Both XOR-swizzled: byte_in_row ^= (row&7)<<4. Two buffers = 64 KB
    // => 2 blocks/CU (the round-5 128KB config was 1 block/CU, lockstep-stalled).
    __shared__ __align__(16) char lds[2 * BUFSZ];

    const int tid  = threadIdx.x;
    const int lane = tid & 63;
    const int wave = tid >> 6;

    // bijective XCD-chunked swizzle (m204): nwg=1010, q=126, r=2
    const int orig = blockIdx.x;
    const int xcd  = orig & 7;
    const int idx8 = orig >> 3;
    const int wg   = (xcd < 2 ? xcd * 127 : 254 + (xcd - 2) * 126) + idx8;
    const int mblk = wg >> 1;                   // adjacent wgs share the A-tile
    const int nblk = wg & 1;
    const int pbase = mblk * BM;
    const int co0   = nblk * BN;

    // ---- A staging: coalesced 16 thr/row, 16 B each; round r covers rows r*16..r*16+15
    const int acol16 = tid & 15;
    const int arow0  = tid >> 4;               // 0..15
    int arowbase[8];
#pragma unroll
    for (int r = 0; r < 8; ++r) {
        int p = pbase + r * 16 + arow0;
        if (p > OHW - 1) p = OHW - 1;          // clamp; stores guarded
        int oy = p / 254;
        int ox = p - oy * 254;
        arowbase[r] = (oy * WW + ox) * CIN;    // float index of pixel base
    }
    // rows r*16+arow0 ≡ arow0 (mod 8)  => one swizzle class for all rounds
    const int aswz  = (arow0 & 7) << 4;
    const int adst0 = arow0 * 128 + ((acol16 * 8) ^ aswz);   // + r*2048 per round

    // ---- B staging: linear gload_lds dest, inverse-swizzled source
    int bsrc[4];
#pragma unroll
    for (int it = 0; it < 4; ++it) {
        int z    = it * 4096 + wave * 1024 + lane * 16;
        int co   = z >> 7;                     // 0..127
        int colb = (z & 127) ^ ((co & 7) << 4);
        bsrc[it] = (co0 + co) * KTOT + (colb >> 1);
    }

    // ---- fragment constants: 4 waves as 2x2, 64x64 per wave
    const int wr64  = (wave >> 1) * 64;
    const int wc64  = (wave & 1) * 64;
    const int llo   = lane & 15;
    const int lhi16 = (lane >> 4) * 16;

    f32x4 acc[4][4];
#pragma unroll
    for (int m = 0; m < 4; m++)
#pragma unroll
        for (int n = 0; n < 4; n++) acc[m][n] = (f32x4)0.f;

    float4v fr[8];       // A staging regs (one K-tile deep)
    short8  af[4], bfr[4];

#define ISSUE_A(tk) do {                                                        \
    int q_ = (tk) >> 1;  int ki_ = q_ / 3;  int kj_ = q_ - ki_ * 3;             \
    int aoff = (ki_ * WW + kj_) * CIN + (((tk) & 1) << 6) + acol16 * 4;         \
    _Pragma("unroll")                                                           \
    for (int r = 0; r < 8; ++r)                                                 \
        fr[r] = *(const float4v*)(x + arowbase[r] + aoff);                      \
} while (0)

#define WRITE_A(bufb) do {                                                      \
    _Pragma("unroll")                                                           \
    for (int r = 0; r < 8; ++r) {                                               \
        uint2v U;                                                               \
        U.x = cvtpk(fr[r][0], fr[r][1]);                                        \
        U.y = cvtpk(fr[r][2], fr[r][3]);                                        \
        *(uint2v*)(lds + (bufb) + adst0 + r * 2048) = U;                        \
    }                                                                           \
} while (0)

#define GLOAD_B(bufb, tk) do {                                                  \
    _Pragma("unroll")                                                           \
    for (int it = 0; it < 4; ++it)                                              \
        gload16(wt + bsrc[it] + (tk) * 64,                                      \
                lds + (bufb) + 16384 + it * 4096 + wave * 1024);                \
} while (0)

#define READ_B(bufb, kk) do {                                                   \
    _Pragma("unroll")                                                           \
    for (int n = 0; n < 4; ++n) {                                               \
        int co  = wc64 + n * 16 + llo;                                          \
        int off = co * 128 + (((kk) * 64 + lhi16) ^ ((co & 7) << 4));           \
        bfr[n] = *(const short8*)(lds + (bufb) + 16384 + off);                  \
    }                                                                           \
} while (0)

#define READ_A(bufb, kk) do {                                                   \
    _Pragma("unroll")                                                           \
    for (int mi = 0; mi < 4; ++mi) {                                            \
        int row = wr64 + mi * 16 + llo;                                         \
        int off = row * 128 + (((kk) * 64 + lhi16) ^ ((row & 7) << 4));         \
        af[mi] = *(const short8*)(lds + (bufb) + off);                          \
    }                                                                           \
} while (0)

#define MFMA16() do {                                                           \
    __builtin_amdgcn_s_setprio(1);                                              \
    _Pragma("unroll")                                                           \
    for (int mi = 0; mi < 4; ++mi)                                              \
        _Pragma("unroll")                                                       \
        for (int n = 0; n < 4; ++n)                                             \
            acc[mi][n] = __builtin_amdgcn_mfma_f32_16x16x32_bf16(               \
                af[mi], bfr[n], acc[mi][n], 0, 0, 0);                           \
    __builtin_amdgcn_s_setprio(0);                                              \
} while (0)

// One K-tile = 2 phases (kk=0,1), 16 MFMA each.
// Stage ledger: entry issues A(8, oldest) then B-gload(4, newest);
// ph1 vmcnt(4) drains exactly A; tile-end vmcnt(0) drains B (issued
// ~2 phases earlier) BEFORE the end barrier => cross-wave gload
// visibility. A ds_writes drained by own post-BAR lgkm(0) before end-BAR.
#define TILE(CUR, NXT, TK1, DOSTAGE) do {                                       \
    if (DOSTAGE) { ISSUE_A(TK1); GLOAD_B(NXT, TK1); }                           \
    /* ph0 */                                                                   \
    READ_A(CUR, 0); READ_B(CUR, 0);                                             \
    SB; BAR; WAIT_LGKM; SB; MFMA16(); SB; BAR; SB;                              \
    /* ph1 */                                                                   \
    READ_A(CUR, 1); READ_B(CUR, 1);                                             \
    if (DOSTAGE) { WAIT_VM(4); WRITE_A(NXT); }                                  \
    SB; BAR; WAIT_LGKM; SB; MFMA16(); SB;                                       \
    if (DOSTAGE) { WAIT_VM(0); }                                                \
    BAR; SB;                                                                    \
} while (0)

    // ---- prologue: stage tile 0 into buf0
    ISSUE_A(0);
    GLOAD_B(0, 0);
    WAIT_VM(4);            // A regs landed (8 oldest of 12)
    WRITE_A(0);
    WAIT_VM(0);            // B gloads landed
    WAIT_LGKM;             // A ds_writes visible
    SB; BAR; SB;

    // ---- main loop: tiles 0..16 stage t+1; tile 17 compute-only
#pragma unroll 2
    for (int t = 0; t < 16; t += 2) {
        TILE(0,     BUFSZ, t + 1, 1);
        TILE(BUFSZ, 0,     t + 2, 1);
    }
    TILE(0,     BUFSZ, 17, 1);
    TILE(BUFSZ, 0,     0,  0);

    // ---- epilogue: n-innermost, 16-lane-contiguous 64B stores
    const float scl = scale_p[0];
    const int lhi4 = (lane >> 4) * 4;
    float bv[4];
#pragma unroll
    for (int n = 0; n < 4; ++n) bv[n] = bias[co0 + wc64 + n * 16 + llo];
#pragma unroll
    for (int m = 0; m < 4; ++m) {
#pragma unroll
        for (int r = 0; r < 4; ++r) {
            const int pp = pbase + wr64 + m * 16 + lhi4 + r;
            if (pp < OHW) {
#pragma unroll
                for (int n = 0; n < 4; ++n)
                    out[pp * COUT + co0 + wc64 + n * 16 + llo] = acc[m][n][r] * scl + bv[n];
            }
        }
    }
#undef ISSUE_A
#undef WRITE_A
#undef GLOAD_B
#undef READ_B
#undef READ_A
#undef MFMA16
#undef TILE
}

extern "C" void kernel_launch(void* const* d_in, const int* in_sizes, int n_in,
                              void* d_out, int out_size, void* d_ws, size_t ws_size,
                              hipStream_t stream) {
    const float* x     = (const float*)d_in[0];
    const int*   kq    = (const int*)d_in[1];
    const float* scale = (const float*)d_in[2];
    const float* bias  = (const float*)d_in[3];
    float*       out   = (float*)d_out;
    unsigned short* wt = (unsigned short*)d_ws;    // 589,824 B (proven-safe size)

    prep_weights<<<KTOT, 256, 0, stream>>>(kq, wt);
    conv_gemm<<<NWG, 256, 0, stream>>>(x, wt, scale, bias, out);
}

// Round 8
// 131.840 us; speedup vs baseline: 1.0615x; 1.0615x over previous
//
#include <hip/hip_runtime.h>
#include <stdint.h>

#define WW 256
#define CIN 128
#define COUT 256
#define OHW 64516          // 254*254
#define KTOT 1152          // 128*9
#define NSTEP 18           // KTOT/64

typedef __attribute__((ext_vector_type(8))) short short8;
typedef __attribute__((ext_vector_type(4))) float float4v;
typedef __attribute__((ext_vector_type(4))) float f32x4;
typedef __attribute__((ext_vector_type(2))) unsigned int uint2v;

__device__ __forceinline__ short f2bf(float f) {
    unsigned u = __builtin_bit_cast(unsigned, f);
    unsigned r = u + 0x7fffu + ((u >> 16) & 1u);   // RNE
    return (short)(r >> 16);
}

// Wt[co][k'] bf16, k' = q*128 + c. Output-indexed => coalesced writes.
__global__ void prep_weights(const int* __restrict__ kq, unsigned short* __restrict__ wt) {
    int o  = blockIdx.x * 256 + threadIdx.x;   // o = co*1152 + kp
    int co = o / KTOT;
    int kp = o - co * KTOT;
    int q  = kp >> 7;
    int c  = kp & 127;
    wt[o] = (unsigned short)f2bf((float)kq[(c * 9 + q) * 256 + co]);
}

// x fp32 -> bf16 image, both sides coalesced. 8 elems/thread, 4096 blocks exact.
__global__ void cvt_x(const float* __restrict__ x, unsigned short* __restrict__ xb) {
    int i = blockIdx.x * 256 + threadIdx.x;
    float4v a = ((const float4v*)x)[i * 2];
    float4v b = ((const float4v*)x)[i * 2 + 1];
    short8 r;
    r[0]=f2bf(a[0]); r[1]=f2bf(a[1]); r[2]=f2bf(a[2]); r[3]=f2bf(a[3]);
    r[4]=f2bf(b[0]); r[5]=f2bf(b[1]); r[6]=f2bf(b[2]); r[7]=f2bf(b[3]);
    ((short8*)xb)[i] = r;
}

__device__ __forceinline__ void gload16(const void* g, void* l) {
    __builtin_amdgcn_global_load_lds(
        (const __attribute__((address_space(1))) unsigned int*)g,
        (__attribute__((address_space(3))) unsigned int*)l, 16, 0, 0);
}

__device__ __forceinline__ unsigned cvtpk(float lo, float hi) {
    unsigned r;
    asm("v_cvt_pk_bf16_f32 %0, %1, %2" : "=v"(r) : "v"(lo), "v"(hi));
    return r;
}

#define SB  __builtin_amdgcn_sched_barrier(0)
#define BAR __builtin_amdgcn_s_barrier()
#define WAIT_VM(n) asm volatile("s_waitcnt vmcnt(" #n ")" ::: "memory")
#define WAIT_LGKM  asm volatile("s_waitcnt lgkmcnt(0)" ::: "memory")

// ======================= PRIMARY: pure-gload_lds 8-phase =====================
// 256x256 tile, BK=64, 8 waves (2x4), 4 phases/tile, 2 gload_lds/phase.
// RACE-SAFE drain rule: a staged unit's vmcnt-retire sits BEFORE the
// post-MFMA barrier of the phase PRECEDING its first ds_read.
__global__ __launch_bounds__(512, 2) void conv_gemm_bf(
    const unsigned short* __restrict__ xb,
    const unsigned short* __restrict__ wt,
    const float* __restrict__ scale_p,
    const float* __restrict__ bias,
    float* __restrict__ out)
{
    // Per buffer (64KB): A [256 rows][128 B] at +0, B [256 co][128 B] at +32768.
    // Both XOR-swizzled byte^=(row&7)<<4, realized as linear gload_lds dest +
    // inverse-swizzled per-lane global source (rule 21).
    __shared__ __align__(16) char lds[2 * 65536];

    const int tid  = threadIdx.x;
    const int lane = tid & 63;
    const int wave = tid >> 6;

    // bijective XCD-chunked swizzle (m204): nwg=253, q=31, r=5
    const int orig = blockIdx.x;
    const int xcd  = orig & 7;
    const int idx8 = orig >> 3;
    const int wg   = (xcd < 5 ? xcd * 32 : 160 + (xcd - 5) * 31) + idx8;
    const int pbase = wg * 256;

    // ---- staging source addresses (per-lane, inverse-swizzled)
    // unit it covers LDS rows it*64..it*64+63; slot z = it*8192 + tid*16
    int asrc[4];   // xb element offset: pixbase(row) + colb/2   (+AOFF(tk))
    int bsrc[4];   // wt element offset: row*KTOT + colb/2       (+tk*64)
#pragma unroll
    for (int it = 0; it < 4; ++it) {
        int z    = it * 8192 + tid * 16;
        int row  = z >> 7;
        int colb = (z & 127) ^ ((row & 7) << 4);
        int p    = pbase + row;
        if (p > OHW - 1) p = OHW - 1;          // clamp; stores guarded
        int oy = p / 254;
        int ox = p - oy * 254;
        asrc[it] = (oy * WW + ox) * CIN + (colb >> 1);
        bsrc[it] = row * KTOT + (colb >> 1);
    }

    // ---- fragment constants: 8 waves as 2x4, 128x64 per wave
    const int wr128 = (wave >> 2) * 128;
    const int wc64  = (wave & 3) * 64;
    const int llo   = lane & 15;
    const int lhi16 = (lane >> 4) * 16;

    f32x4 acc[8][4];
#pragma unroll
    for (int m = 0; m < 8; m++)
#pragma unroll
        for (int n = 0; n < 4; n++) acc[m][n] = (f32x4)0.f;

    short8 af[4], bfr[4];

#define AOFF(tk) (((((tk) >> 1) / 3) * WW + (((tk) >> 1) % 3)) * CIN + (((tk) & 1) << 6))

#define GLOAD_A1(bufb, tk, it) \
    gload16(xb + asrc[it] + AOFF(tk), lds + (bufb) + (it) * 8192 + tid * 16)

#define GLOAD_B1(bufb, tk, it) \
    gload16(wt + bsrc[it] + (tk) * 64, lds + (bufb) + 32768 + (it) * 8192 + tid * 16)

#define READ_B(bufb, kk) do {                                                   \
    _Pragma("unroll")                                                           \
    for (int n = 0; n < 4; ++n) {                                               \
        int co  = wc64 + n * 16 + llo;                                          \
        int off = co * 128 + (((kk) * 64 + lhi16) ^ ((co & 7) << 4));           \
        bfr[n] = *(const short8*)(lds + (bufb) + 32768 + off);                  \
    }                                                                           \
} while (0)

#define READ_A(bufb, mh, kk) do {                                               \
    _Pragma("unroll")                                                           \
    for (int mi = 0; mi < 4; ++mi) {                                            \
        int row = wr128 + (mh) * 64 + mi * 16 + llo;                            \
        int off = row * 128 + (((kk) * 64 + lhi16) ^ ((row & 7) << 4));         \
        af[mi] = *(const short8*)(lds + (bufb) + off);                          \
    }                                                                           \
} while (0)

#define MFMA16(mh) do {                                                         \
    __builtin_amdgcn_s_setprio(1);                                              \
    _Pragma("unroll")                                                           \
    for (int mi = 0; mi < 4; ++mi)                                              \
        _Pragma("unroll")                                                       \
        for (int n = 0; n < 4; ++n)                                             \
            acc[(mh) * 4 + mi][n] = __builtin_amdgcn_mfma_f32_16x16x32_bf16(    \
                af[mi], bfr[n], acc[(mh) * 4 + mi][n], 0, 0, 0);                \
    __builtin_amdgcn_s_setprio(0);                                              \
} while (0)

// Tile t (4 phases). Stage order (tile t+1): ph0 B0,B1; ph1 B2,B3;
// ph2 A0,A2 (mh=0 rows for both wave-groups); ph3 A1,A3.
// vmcnt ledger (steady state): enter tile with {A1,A3} of THIS tile in
// flight (2). ph0-end WAIT_VM(2) retires them (first read: ph1) while
// keeping B'0,B'1. ph3-end WAIT_VM(2) retires B'0-3+A'0+A'2 (first read:
// t+1.ph0), keeps A'1,A'3 across the boundary. Never 0 in the loop.
#define TILE(CUR, NXT, TK1, DOSTAGE) do {                                       \
    /* ph0: (mh0,kk0) */                                                        \
    READ_B(CUR, 0); READ_A(CUR, 0, 0);                                          \
    if (DOSTAGE) { GLOAD_B1(NXT, TK1, 0); GLOAD_B1(NXT, TK1, 1); }              \
    SB; BAR; WAIT_LGKM; SB; MFMA16(0); SB;                                      \
    if (DOSTAGE) { WAIT_VM(2); } else { WAIT_VM(0); }                           \
    BAR; SB;                                                                    \
    /* ph1: (mh1,kk0) */                                                        \
    READ_A(CUR, 1, 0);                                                          \
    if (DOSTAGE) { GLOAD_B1(NXT, TK1, 2); GLOAD_B1(NXT, TK1, 3); }              \
    SB; BAR; WAIT_LGKM; SB; MFMA16(1); SB; BAR; SB;                             \
    /* ph2: (mh0,kk1) */                                                        \
    READ_B(CUR, 1); READ_A(CUR, 0, 1);                                          \
    if (DOSTAGE) { GLOAD_A1(NXT, TK1, 0); GLOAD_A1(NXT, TK1, 2); }              \
    SB; BAR; WAIT_LGKM; SB; MFMA16(0); SB; BAR; SB;                             \
    /* ph3: (mh1,kk1) */                                                        \
    READ_A(CUR, 1, 1);                                                          \
    if (DOSTAGE) { GLOAD_A1(NXT, TK1, 1); GLOAD_A1(NXT, TK1, 3); }              \
    SB; BAR; WAIT_LGKM; SB; MFMA16(1); SB;                                      \
    WAIT_VM(2);                                                                 \
    BAR; SB;                                                                    \
} while (0)

    // ---- prologue: stage tile 0 fully, full drain, barrier
    GLOAD_B1(0, 0, 0); GLOAD_B1(0, 0, 1); GLOAD_B1(0, 0, 2); GLOAD_B1(0, 0, 3);
    GLOAD_A1(0, 0, 0); GLOAD_A1(0, 0, 2); GLOAD_A1(0, 0, 1); GLOAD_A1(0, 0, 3);
    WAIT_VM(0);
    SB; BAR; SB;

    // ---- main loop: tiles 0..16 stage t+1; tile 17 compute-only
#pragma unroll 2
    for (int t = 0; t < 16; t += 2) {
        TILE(0,     65536, t + 1, 1);
        TILE(65536, 0,     t + 2, 1);
    }
    TILE(0,     65536, 17, 1);     // tile 16
    TILE(65536, 0,     0,  0);     // tile 17 (tail: ph0 drains to 0)

    // ---- epilogue: n-innermost, 64B-contiguous quarter-wave stores
    const float scl = scale_p[0];
    const int lhi4 = (lane >> 4) * 4;
    float bv[4];
#pragma unroll
    for (int n = 0; n < 4; ++n) bv[n] = bias[wc64 + n * 16 + llo];
#pragma unroll
    for (int m = 0; m < 8; ++m) {
#pragma unroll
        for (int r = 0; r < 4; ++r) {
            const int pp = pbase + wr128 + m * 16 + lhi4 + r;
            if (pp < OHW) {
#pragma unroll
                for (int n = 0; n < 4; ++n)
                    out[pp * COUT + wc64 + n * 16 + llo] = acc[m][n][r] * scl + bv[n];
            }
        }
    }
#undef GLOAD_A1
#undef GLOAD_B1
#undef READ_B
#undef READ_A
#undef MFMA16
#undef TILE
#undef AOFF
}

// ======================= FALLBACK: round-5 kernel (fp32 A, reg-staged) ========
// Used only if ws_size can't hold the bf16 image. Proven: 60 us, absmax 0.5.
__global__ __launch_bounds__(512, 2) void conv_gemm_f32(
    const float* __restrict__ x,
    const unsigned short* __restrict__ wt,
    const float* __restrict__ scale_p,
    const float* __restrict__ bias,
    float* __restrict__ out)
{
    __shared__ __align__(16) char lds[2 * 65536];
    const int tid  = threadIdx.x;
    const int lane = tid & 63;
    const int wave = tid >> 6;
    const int orig = blockIdx.x;
    const int xcd  = orig & 7;
    const int idx8 = orig >> 3;
    const int wg   = (xcd < 5 ? xcd * 32 : 160 + (xcd - 5) * 31) + idx8;
    const int pbase = wg * 256;

    const int acol16 = tid & 15;
    const int arow0  = tid >> 4;
    int arowbase[8];
#pragma unroll
    for (int r = 0; r < 8; ++r) {
        int p = pbase + arow0 + r * 32;
        if (p > OHW - 1) p = OHW - 1;
        int oy = p / 254;
        int ox = p - oy * 254;
        arowbase[r] = (oy * WW + ox) * CIN;
    }
    const int aswz  = (arow0 & 7) << 4;
    const int adst0 = arow0 * 128 + ((acol16 * 8) ^ aswz);

    int bsrc[4];
#pragma unroll
    for (int it = 0; it < 4; ++it) {
        int z    = it * 8192 + wave * 1024 + lane * 16;
        int co   = z >> 7;
        int colb = (z & 127) ^ ((co & 7) << 4);
        bsrc[it] = co * KTOT + (colb >> 1);
    }
    const int wr128 = (wave >> 2) * 128;
    const int wc64  = (wave & 3) * 64;
    const int llo   = lane & 15;
    const int lhi16 = (lane >> 4) * 16;

    f32x4 acc[8][4];
#pragma unroll
    for (int m = 0; m < 8; m++)
#pragma unroll
        for (int n = 0; n < 4; n++) acc[m][n] = (f32x4)0.f;
    float4v fr[8];
    short8  af[4], bfr[4];

#define ISSUE_A(lo_, tk) do {                                                   \
    int q_ = (tk) >> 1;  int ki_ = q_ / 3;  int kj_ = q_ - ki_ * 3;             \
    int aoff = (ki_ * WW + kj_) * CIN + (((tk) & 1) << 6) + acol16 * 4;         \
    _Pragma("unroll")                                                           \
    for (int r = (lo_); r < (lo_) + 4; ++r)                                     \
        fr[r] = *(const float4v*)(x + arowbase[r] + aoff);                      \
} while (0)
#define WRITE_A(bufb, lo_) do {                                                 \
    _Pragma("unroll")                                                           \
    for (int r = (lo_); r < (lo_) + 4; ++r) {                                   \
        uint2v U;                                                               \
        U.x = cvtpk(fr[r][0], fr[r][1]);                                        \
        U.y = cvtpk(fr[r][2], fr[r][3]);                                        \
        *(uint2v*)(lds + (bufb) + adst0 + r * 4096) = U;                        \
    }                                                                           \
} while (0)
#define GLOAD_B(bufb, tk) do {                                                  \
    _Pragma("unroll")                                                           \
    for (int it = 0; it < 4; ++it)                                              \
        gload16(wt + bsrc[it] + (tk) * 64,                                      \
                lds + (bufb) + 32768 + it * 8192 + wave * 1024);                \
} while (0)
#define READ_B2(bufb, kk) do {                                                  \
    _Pragma("unroll")                                                           \
    for (int n = 0; n < 4; ++n) {                                               \
        int co  = wc64 + n * 16 + llo;                                          \
        int off = co * 128 + (((kk) * 64 + lhi16) ^ ((co & 7) << 4));           \
        bfr[n] = *(const short8*)(lds + (bufb) + 32768 + off);                  \
    }                                                                           \
} while (0)
#define READ_A2(bufb, mh, kk) do {                                              \
    _Pragma("unroll")                                                           \
    for (int mi = 0; mi < 4; ++mi) {                                            \
        int row = wr128 + (mh) * 64 + mi * 16 + llo;                            \
        int off = row * 128 + (((kk) * 64 + lhi16) ^ ((row & 7) << 4));         \
        af[mi] = *(const short8*)(lds + (bufb) + off);                          \
    }                                                                           \
} while (0)
#define MFMA16B(mh) do {                                                        \
    __builtin_amdgcn_s_setprio(1);                                              \
    _Pragma("unroll")                                                           \
    for (int mi = 0; mi < 4; ++mi)                                              \
        _Pragma("unroll")                                                       \
        for (int n = 0; n < 4; ++n)                                             \
            acc[(mh) * 4 + mi][n] = __builtin_amdgcn_mfma_f32_16x16x32_bf16(    \
                af[mi], bfr[n], acc[(mh) * 4 + mi][n], 0, 0, 0);                \
    __builtin_amdgcn_s_setprio(0);                                              \
} while (0)
#define TILEF(CUR, NXT, TK1, DOSTAGE) do {                                      \
    READ_B2(CUR, 0); READ_A2(CUR, 0, 0);                                        \
    if (DOSTAGE) { GLOAD_B(NXT, TK1); ISSUE_A(0, TK1); }                        \
    SB; BAR; WAIT_LGKM; SB; MFMA16B(0); SB; BAR; SB;                            \
    READ_A2(CUR, 1, 0);                                                         \
    if (DOSTAGE) { ISSUE_A(4, TK1); }                                           \
    SB; BAR; WAIT_LGKM; SB; MFMA16B(1); SB; BAR; SB;                            \
    READ_B2(CUR, 1); READ_A2(CUR, 0, 1);                                        \
    if (DOSTAGE) { WAIT_VM(4); WRITE_A(NXT, 0); }                               \
    SB; BAR; WAIT_LGKM; SB; MFMA16B(0); SB; BAR; SB;                            \
    READ_A2(CUR, 1, 1);                                                         \
    if (DOSTAGE) { WAIT_VM(0); WRITE_A(NXT, 4); }                               \
    SB; BAR; WAIT_LGKM; SB; MFMA16B(1); SB; BAR; SB;                            \
} while (0)

    GLOAD_B(0, 0);
    ISSUE_A(0, 0);
    ISSUE_A(4, 0);
    WAIT_VM(0);
    WRITE_A(0, 0);
    WRITE_A(0, 4);
    WAIT_LGKM; SB; BAR; SB;
#pragma unroll 2
    for (int t = 0; t < 16; t += 2) {
        TILEF(0,     65536, t + 1, 1);
        TILEF(65536, 0,     t + 2, 1);
    }
    TILEF(0,     65536, 17, 1);
    TILEF(65536, 0,     0,  0);

    const float scl = scale_p[0];
    const int lhi4 = (lane >> 4) * 4;
    float bv[4];
#pragma unroll
    for (int n = 0; n < 4; ++n) bv[n] = bias[wc64 + n * 16 + llo];
#pragma unroll
    for (int m = 0; m < 8; ++m) {
#pragma unroll
        for (int r = 0; r < 4; ++r) {
            const int pp = pbase + wr128 + m * 16 + lhi4 + r;
            if (pp < OHW) {
#pragma unroll
                for (int n = 0; n < 4; ++n)
                    out[pp * COUT + wc64 + n * 16 + llo] = acc[m][n][r] * scl + bv[n];
            }
        }
    }
#undef ISSUE_A
#undef WRITE_A
#undef GLOAD_B
#undef READ_B2
#undef READ_A2
#undef MFMA16B
#undef TILEF
}

extern "C" void kernel_launch(void* const* d_in, const int* in_sizes, int n_in,
                              void* d_out, int out_size, void* d_ws, size_t ws_size,
                              hipStream_t stream) {
    const float* x     = (const float*)d_in[0];
    const int*   kq    = (const int*)d_in[1];
    const float* scale = (const float*)d_in[2];
    const float* bias  = (const float*)d_in[3];
    float*       out   = (float*)d_out;

    unsigned short* wt = (unsigned short*)d_ws;                       // 589,824 B
    unsigned short* xb = (unsigned short*)((char*)d_ws + 589824);     // 16,777,216 B

    prep_weights<<<KTOT, 256, 0, stream>>>(kq, wt);

    if (ws_size >= (size_t)589824 + 16777216) {
        cvt_x<<<4096, 256, 0, stream>>>(x, xb);
        conv_gemm_bf<<<253, 512, 0, stream>>>(xb, wt, scale, bias, out);
    } else {
        conv_gemm_f32<<<253, 512, 0, stream>>>(x, wt, scale, bias, out);
    }
}